// Round 7
// baseline (729.346 us; speedup 1.0000x reference)
//
#include <hip/hip_runtime.h>
#include <math.h>

#define PLANE 4352   // 64 rows * 68 shorts
#define RS 68        // row stride (elements); 136 B = 34 banks -> 2-way max, free

typedef short s4v __attribute__((ext_vector_type(4)));
typedef short s8v __attribute__((ext_vector_type(8)));
typedef float f16v __attribute__((ext_vector_type(16)));

__device__ __forceinline__ float fb(short s) {
  return __uint_as_float(((unsigned)(unsigned short)s) << 16);
}

// RNE-packed f32x2 -> bf16x2 (low = e0, high = e1). No builtin on gfx950.
__device__ __forceinline__ unsigned cvt_pk_bf16(float e0, float e1) {
  unsigned r;
  asm("v_cvt_pk_bf16_f32 %0, %1, %2" : "=v"(r) : "v"(e0), "v"(e1));
  return r;
}

// Load hi/lo fragment sets of symmetric matrix quadrant q (X planes):
// lane (lr,h) gets rows 32q+lr, cols ks*16+8h..+7  (A-frag == B-frag by symmetry)
__device__ __forceinline__ void load_fs(const short* Ph, const short* Pl, int q,
                                        int lr, int h, s8v fh[4], s8v fl[4]) {
  const int off = (32 * q + lr) * RS + 8 * h;
  const short* ph = Ph + off;
  const short* pl = Pl + off;
#pragma unroll
  for (int ks = 0; ks < 4; ++ks) {
    s4v a = *(const s4v*)(ph + 16 * ks);
    s4v b = *(const s4v*)(ph + 16 * ks + 4);
    fh[ks] = __builtin_shufflevector(a, b, 0, 1, 2, 3, 4, 5, 6, 7);
    s4v c = *(const s4v*)(pl + 16 * ks);
    s4v d = *(const s4v*)(pl + 16 * ks + 4);
    fl[ks] = __builtin_shufflevector(c, d, 0, 1, 2, 3, 4, 5, 6, 7);
  }
}

// Load single-plane fragment set of symmetric matrix quadrant q
__device__ __forceinline__ void load_fs1(const short* P, int q, int lr, int h,
                                         s8v f[4]) {
  const int off = (32 * q + lr) * RS + 8 * h;
  const short* p = P + off;
#pragma unroll
  for (int ks = 0; ks < 4; ++ks) {
    s4v a = *(const s4v*)(p + 16 * ks);
    s4v b = *(const s4v*)(p + 16 * ks + 4);
    f[ks] = __builtin_shufflevector(a, b, 0, 1, 2, 3, 4, 5, 6, 7);
  }
}

// A,B both hi/lo: 12 MFMAs (drop lo*lo ~ 2^-32)
__device__ __forceinline__ f16v mm3p(const s8v Ah[4], const s8v Al[4],
                                     const s8v Bh[4], const s8v Bl[4]) {
  f16v acc = {0.f, 0.f, 0.f, 0.f, 0.f, 0.f, 0.f, 0.f,
              0.f, 0.f, 0.f, 0.f, 0.f, 0.f, 0.f, 0.f};
#pragma unroll
  for (int ks = 0; ks < 4; ++ks) {
    acc = __builtin_amdgcn_mfma_f32_32x32x16_bf16(Ah[ks], Bh[ks], acc, 0, 0, 0);
    acc = __builtin_amdgcn_mfma_f32_32x32x16_bf16(Ah[ks], Bl[ks], acc, 0, 0, 0);
    acc = __builtin_amdgcn_mfma_f32_32x32x16_bf16(Al[ks], Bh[ks], acc, 0, 0, 0);
  }
  return acc;
}

// A single, B hi/lo: 8 MFMAs
__device__ __forceinline__ f16v mm2p(const s8v Ah[4], const s8v Bh[4],
                                     const s8v Bl[4]) {
  f16v acc = {0.f, 0.f, 0.f, 0.f, 0.f, 0.f, 0.f, 0.f,
              0.f, 0.f, 0.f, 0.f, 0.f, 0.f, 0.f, 0.f};
#pragma unroll
  for (int ks = 0; ks < 4; ++ks) {
    acc = __builtin_amdgcn_mfma_f32_32x32x16_bf16(Ah[ks], Bh[ks], acc, 0, 0, 0);
    acc = __builtin_amdgcn_mfma_f32_32x32x16_bf16(Ah[ks], Bl[ks], acc, 0, 0, 0);
  }
  return acc;
}

// A,B both single: 4 MFMAs
__device__ __forceinline__ f16v mm1p(const s8v Ah[4], const s8v Bh[4]) {
  f16v acc = {0.f, 0.f, 0.f, 0.f, 0.f, 0.f, 0.f, 0.f,
              0.f, 0.f, 0.f, 0.f, 0.f, 0.f, 0.f, 0.f};
#pragma unroll
  for (int ks = 0; ks < 4; ++ks)
    acc = __builtin_amdgcn_mfma_f32_32x32x16_bf16(Ah[ks], Bh[ks], acc, 0, 0, 0);
  return acc;
}

// Transposed single-plane store of quadrant result (symmetric matrices):
// LDS[32qb+lr][32qa + (t+8g+4h)] = v[4g+t] (RNE bf16).
__device__ __forceinline__ void store_s(const f16v v, short* P, int qa, int qb,
                                        int lr, int h) {
  const int off = (32 * qb + lr) * RS + 32 * qa + 4 * h;
  short* p = P + off;
#pragma unroll
  for (int g = 0; g < 4; ++g) {
    unsigned h01 = cvt_pk_bf16(v[4 * g], v[4 * g + 1]);
    unsigned h23 = cvt_pk_bf16(v[4 * g + 2], v[4 * g + 3]);
    *(uint2*)(p + 8 * g) = make_uint2(h01, h23);
  }
}

// Transposed single-plane combo store: aa*v + bx*Xs + cx*X2s (+ad on diagonal).
__device__ __forceinline__ void store_sc(const f16v v, short* P, int qa, int qb,
                                         int lr, int h, float aa, float bx,
                                         float cx, float ad, const float Xs[16],
                                         const f16v X2s, int diagq) {
  const int off = (32 * qb + lr) * RS + 32 * qa + 4 * h;
  short* p = P + off;
#pragma unroll
  for (int g = 0; g < 4; ++g) {
    float x[4];
#pragma unroll
    for (int t = 0; t < 4; ++t) {
      const int idx = 4 * g + t;
      x[t] = aa * v[idx] + bx * Xs[idx] + cx * X2s[idx];
      if (diagq && (t + 8 * g + 4 * h) == lr) x[t] += ad;
    }
    unsigned h01 = cvt_pk_bf16(x[0], x[1]);
    unsigned h23 = cvt_pk_bf16(x[2], x[3]);
    *(uint2*)(p + 8 * g) = make_uint2(h01, h23);
  }
}

extern "C" __global__ void __launch_bounds__(256, 6)
logeig_kernel(const float* __restrict__ in, float* __restrict__ out) {
  // 3 LDS planes only (26.1 KB) -> 6 blocks/CU.
  // Plane lifecycle:  Yh: X-hi -> G2 (S2)   Yl: X-lo -> W=X^3 (S2)
  //                   Zh: X^2  -> P1 (H)
  __shared__ __align__(16) short sm[3 * PLANE];
  __shared__ float red[4];

  const int b = blockIdx.x, tid = threadIdx.x;
  short* Yh = sm;
  short* Yl = sm + PLANE;
  short* Zh = sm + 2 * PLANE;

  // ---- direct global -> register load (no LDS staging round-trip) ----
  // Thread owns row rr, cols cc*16..+15 (64B/lane chunks; L2 absorbs stride).
  const int rr = tid >> 2, cc = tid & 3;
  float av[16];
  {
    const float* Ab = in + (size_t)b * 4096 + rr * 64 + cc * 16;
#pragma unroll
    for (int i = 0; i < 4; ++i) {
      float4 v = *(const float4*)(Ab + 4 * i);
      av[4 * i] = v.x; av[4 * i + 1] = v.y;
      av[4 * i + 2] = v.z; av[4 * i + 3] = v.w;
    }
  }

  // ---- c = ||A||_inf ----
  // A = PSD + I => spectrum(A) subset [1, c] EXACTLY (lmin >= 1, c >= lmax).
  {
    float s = 0.f;
#pragma unroll
    for (int i = 0; i < 16; ++i) s += fabsf(av[i]);
    s += __shfl_xor(s, 1);
    s += __shfl_xor(s, 2);
#pragma unroll
    for (int off = 4; off < 64; off <<= 1) s = fmaxf(s, __shfl_xor(s, off));
    if ((tid & 63) == 0) red[tid >> 6] = s;
  }
  __syncthreads();
  const float c = fmaxf(fmaxf(red[0], red[1]), fmaxf(red[2], red[3]));

  // ---- closed-form degree-9 Chebyshev approx of log on [1,c] ----
  // X = (2A-(c+1)I)/(c-1); log(alpha+beta*x) = 2 log((sqrt(c)+1)/2)
  //   + 2 sum (-1)^{k+1} (tau^k/k) T_k(x),  tau = (sqrt(c)-1)/(sqrt(c)+1).
  const float rtc = sqrtf(c);
  const float tau = (rtc - 1.0f) / (rtc + 1.0f);
  float A[10];
  {
    float tp = tau;
#pragma unroll
    for (int k = 1; k < 10; ++k) {
      A[k] = 2.0f * tp / (float)k * ((k & 1) ? 1.0f : -1.0f);
      tp *= tau;
    }
  }
  const float b0 = 2.0f * logf((rtc + 1.0f) * 0.5f) - A[2] + A[4] - A[6] + A[8];
  const float b1 = A[1] - 3.f * A[3] + 5.f * A[5] - 7.f * A[7] + 9.f * A[9];
  const float b2 = 2.f * A[2] - 8.f * A[4] + 18.f * A[6] - 32.f * A[8];
  const float b3 = 4.f * A[3] - 20.f * A[5] + 56.f * A[7] - 120.f * A[9];
  const float b4 = 8.f * A[4] - 48.f * A[6] + 160.f * A[8];
  const float b5 = 16.f * A[5] - 112.f * A[7] + 432.f * A[9];
  const float b6 = 32.f * A[6] - 256.f * A[8];
  const float b7 = 64.f * A[7] - 576.f * A[9];
  const float b8 = 128.f * A[8];
  const float b9 = 256.f * A[9];

  // ---- split X = (2A-(c+1)I)/(c-1) into bf16 hi/lo planes ----
  {
    const float sc2 = 2.0f / (c - 1.0f);
    const float sh = (c + 1.0f) / (c - 1.0f);
    short* ph = Yh + rr * RS + cc * 16;
    short* pl = Yl + rr * RS + cc * 16;
#pragma unroll
    for (int i = 0; i < 16; i += 4) {
      float y0 = av[i] * sc2 - ((16 * cc + i) == rr ? sh : 0.f);
      float y1 = av[i + 1] * sc2 - ((16 * cc + i + 1) == rr ? sh : 0.f);
      float y2 = av[i + 2] * sc2 - ((16 * cc + i + 2) == rr ? sh : 0.f);
      float y3 = av[i + 3] * sc2 - ((16 * cc + i + 3) == rr ? sh : 0.f);
      unsigned h01 = cvt_pk_bf16(y0, y1);
      unsigned h23 = cvt_pk_bf16(y2, y3);
      unsigned l01 = cvt_pk_bf16(y0 - __uint_as_float(h01 << 16),
                                 y1 - __uint_as_float(h01 & 0xffff0000u));
      unsigned l23 = cvt_pk_bf16(y2 - __uint_as_float(h23 << 16),
                                 y3 - __uint_as_float(h23 & 0xffff0000u));
      *(uint2*)(ph + i) = make_uint2(h01, h23);
      *(uint2*)(pl + i) = make_uint2(l01, l23);
    }
  }
  __syncthreads();

  const int lane = tid & 63, w = tid >> 6;
  const int lr = lane & 31, h = lane >> 5;
  const int qi = w >> 1, qj = w & 1;
  const int dq = (qi == qj);

  // ---- Paterson-Stockmeyer, W = X^3:  p = G0 + G1 W + G2 W^2,
  //      G2 = b6 I + b7 X + b8 X^2 + b9 X^3  (elementwise, no matmul)
  //      G1 = b3 I + b4 X + b5 X^2,   G0 = b0 I + b1 X + b2 X^2.
  //      4 matmuls: X^2 (hi/lo x hi/lo), X^3 (single x hi/lo),
  //                 P1 = G2*W + G1 (single x single), p = P1*W + G0 (single).
  s8v Xjh[4], Xjl[4];   // X@qj frags (hi/lo), cached through S2
  float Xs[16];         // store-layout X values (f32)
  f16v X2s, X3s;        // store-layout X^2 / X^3 values (= MFMA accs, f32)

  // S1: X^2 -> Zh (single); harvest Xs. After this phase both X planes are
  // dead (Xj cached in regs, Xi consumed, Xs harvested).
  {
    load_fs(Yh, Yl, qj, lr, h, Xjh, Xjl);
    {  // Xs: X at the transposed-store positions (row 32qj+lr, col 32qi+4h+8g+t)
      const int off = (32 * qj + lr) * RS + 32 * qi + 4 * h;
#pragma unroll
      for (int g = 0; g < 4; ++g) {
        s4v vh = *(const s4v*)(Yh + off + 8 * g);
        s4v vl = *(const s4v*)(Yl + off + 8 * g);
#pragma unroll
        for (int t = 0; t < 4; ++t) Xs[4 * g + t] = fb(vh[t]) + fb(vl[t]);
      }
    }
    if (dq) {
      X2s = mm3p(Xjh, Xjl, Xjh, Xjl);
    } else {
      s8v Xih[4], Xil[4];
      load_fs(Yh, Yl, qi, lr, h, Xih, Xil);
      X2s = mm3p(Xih, Xil, Xjh, Xjl);  // X^2 quadrant (qi,qj)
    }
    store_s(X2s, Zh, qi, qj, lr, h);
    __syncthreads();
  }

  // S2: X^3 = W -> Yl (X-lo dead); G2 -> Yh (X-hi dead). Reads only Zh + regs.
  {
    s8v X2i[4];
    load_fs1(Zh, qi, lr, h, X2i);
    X3s = mm2p(X2i, Xjh, Xjl);  // X^3 quadrant (qi,qj), 8 MFMAs
    store_s(X3s, Yl, qi, qj, lr, h);
    // G2 = b6 I + b7 X + b8 X^2 + b9 X^3
    store_sc(X3s, Yh, qi, qj, lr, h, b9, b7, b8, b6, Xs, X2s, dq);
    __syncthreads();
  }

  // H: P1 = G2*W + G1 -> Zh (X^2 plane dead: combos use X2s regs).
  s8v Wh[4];  // W = X^3@qj frags, cached for F
  {
    load_fs1(Yl, qj, lr, h, Wh);
    s8v G2i[4];
    load_fs1(Yh, qi, lr, h, G2i);
    f16v q = mm1p(G2i, Wh);  // 4 MFMAs
    store_sc(q, Zh, qi, qj, lr, h, 1.f, b4, b5, b3, Xs, X2s, dq);
    __syncthreads();
  }

  // F (final): L = P1*W + G0 ; abs, sqrt2 off-diag, triu gather.
  // The (qi>qj) wave's quadrant is discarded: skip it.
  if (qi <= qj) {
    s8v P1i[4];
    load_fs1(Zh, qi, lr, h, P1i);
    f16v fq = mm1p(P1i, Wh);  // quadrant (qi,qj), 4 MFMAs
    const float SQ2 = 1.41421356237309515f;
    float* ob = out + (size_t)b * 2080;
#pragma unroll
    for (int g = 0; g < 4; ++g) {
#pragma unroll
      for (int t = 0; t < 4; ++t) {
        int rexpr = t + 8 * g + 4 * h;
        int R = 32 * qi + rexpr, C = 32 * qj + lr;
        if (qi < qj || rexpr <= lr) {
          const int idx = 4 * g + t;
          float v = fq[idx] + b1 * Xs[idx] + b2 * X2s[idx]
                    + ((dq && rexpr == lr) ? b0 : 0.f);
          v = fabsf(v) * ((R == C) ? 1.f : SQ2);
          ob[(size_t)(R * 64 - (R * (R - 1)) / 2 - R) + C] = v;
        }
      }
    }
  }
}

extern "C" void kernel_launch(void* const* d_in, const int* in_sizes, int n_in,
                              void* d_out, int out_size, void* d_ws, size_t ws_size,
                              hipStream_t stream) {
  (void)n_in; (void)d_ws; (void)ws_size; (void)out_size;
  const float* in = (const float*)d_in[0];
  float* out = (float*)d_out;
  const int B = in_sizes[0] / 4096;  // 16384
  hipLaunchKernelGGL(logeig_kernel, dim3(B), dim3(256), 0, stream, in, out);
}

// Round 8
// 394.953 us; speedup vs baseline: 1.8467x; 1.8467x over previous
//
#include <hip/hip_runtime.h>
#include <math.h>

#define PLANE 4352   // 64 rows * 68 shorts
#define RS 68        // row stride (elements); 136 B = 34 banks -> 2-way max, free

typedef short s4v __attribute__((ext_vector_type(4)));
typedef short s8v __attribute__((ext_vector_type(8)));
typedef float f16v __attribute__((ext_vector_type(16)));

__device__ __forceinline__ float fb(short s) {
  return __uint_as_float(((unsigned)(unsigned short)s) << 16);
}

// RNE-packed f32x2 -> bf16x2 (low = e0, high = e1). No builtin on gfx950.
__device__ __forceinline__ unsigned cvt_pk_bf16(float e0, float e1) {
  unsigned r;
  asm("v_cvt_pk_bf16_f32 %0, %1, %2" : "=v"(r) : "v"(e0), "v"(e1));
  return r;
}

// Load hi/lo fragment sets of symmetric matrix quadrant q (X planes):
// lane (lr,h) gets rows 32q+lr, cols ks*16+8h..+7  (A-frag == B-frag by symmetry)
__device__ __forceinline__ void load_fs(const short* Ph, const short* Pl, int q,
                                        int lr, int h, s8v fh[4], s8v fl[4]) {
  const int off = (32 * q + lr) * RS + 8 * h;
  const short* ph = Ph + off;
  const short* pl = Pl + off;
#pragma unroll
  for (int ks = 0; ks < 4; ++ks) {
    s4v a = *(const s4v*)(ph + 16 * ks);
    s4v b = *(const s4v*)(ph + 16 * ks + 4);
    fh[ks] = __builtin_shufflevector(a, b, 0, 1, 2, 3, 4, 5, 6, 7);
    s4v c = *(const s4v*)(pl + 16 * ks);
    s4v d = *(const s4v*)(pl + 16 * ks + 4);
    fl[ks] = __builtin_shufflevector(c, d, 0, 1, 2, 3, 4, 5, 6, 7);
  }
}

// Load single-plane fragment set of symmetric matrix quadrant q
__device__ __forceinline__ void load_fs1(const short* P, int q, int lr, int h,
                                         s8v f[4]) {
  const int off = (32 * q + lr) * RS + 8 * h;
  const short* p = P + off;
#pragma unroll
  for (int ks = 0; ks < 4; ++ks) {
    s4v a = *(const s4v*)(p + 16 * ks);
    s4v b = *(const s4v*)(p + 16 * ks + 4);
    f[ks] = __builtin_shufflevector(a, b, 0, 1, 2, 3, 4, 5, 6, 7);
  }
}

// A,B both hi/lo: 12 MFMAs (drop lo*lo ~ 2^-32)
__device__ __forceinline__ f16v mm3p(const s8v Ah[4], const s8v Al[4],
                                     const s8v Bh[4], const s8v Bl[4]) {
  f16v acc = {0.f, 0.f, 0.f, 0.f, 0.f, 0.f, 0.f, 0.f,
              0.f, 0.f, 0.f, 0.f, 0.f, 0.f, 0.f, 0.f};
#pragma unroll
  for (int ks = 0; ks < 4; ++ks) {
    acc = __builtin_amdgcn_mfma_f32_32x32x16_bf16(Ah[ks], Bh[ks], acc, 0, 0, 0);
    acc = __builtin_amdgcn_mfma_f32_32x32x16_bf16(Ah[ks], Bl[ks], acc, 0, 0, 0);
    acc = __builtin_amdgcn_mfma_f32_32x32x16_bf16(Al[ks], Bh[ks], acc, 0, 0, 0);
  }
  return acc;
}

// A single, B hi/lo: 8 MFMAs
__device__ __forceinline__ f16v mm2p(const s8v Ah[4], const s8v Bh[4],
                                     const s8v Bl[4]) {
  f16v acc = {0.f, 0.f, 0.f, 0.f, 0.f, 0.f, 0.f, 0.f,
              0.f, 0.f, 0.f, 0.f, 0.f, 0.f, 0.f, 0.f};
#pragma unroll
  for (int ks = 0; ks < 4; ++ks) {
    acc = __builtin_amdgcn_mfma_f32_32x32x16_bf16(Ah[ks], Bh[ks], acc, 0, 0, 0);
    acc = __builtin_amdgcn_mfma_f32_32x32x16_bf16(Ah[ks], Bl[ks], acc, 0, 0, 0);
  }
  return acc;
}

// A,B both single: 4 MFMAs
__device__ __forceinline__ f16v mm1p(const s8v Ah[4], const s8v Bh[4]) {
  f16v acc = {0.f, 0.f, 0.f, 0.f, 0.f, 0.f, 0.f, 0.f,
              0.f, 0.f, 0.f, 0.f, 0.f, 0.f, 0.f, 0.f};
#pragma unroll
  for (int ks = 0; ks < 4; ++ks)
    acc = __builtin_amdgcn_mfma_f32_32x32x16_bf16(Ah[ks], Bh[ks], acc, 0, 0, 0);
  return acc;
}

// Transposed single-plane store of quadrant result (symmetric matrices):
// LDS[32qb+lr][32qa + (t+8g+4h)] = v[4g+t] (RNE bf16).
__device__ __forceinline__ void store_s(const f16v v, short* P, int qa, int qb,
                                        int lr, int h) {
  const int off = (32 * qb + lr) * RS + 32 * qa + 4 * h;
  short* p = P + off;
#pragma unroll
  for (int g = 0; g < 4; ++g) {
    unsigned h01 = cvt_pk_bf16(v[4 * g], v[4 * g + 1]);
    unsigned h23 = cvt_pk_bf16(v[4 * g + 2], v[4 * g + 3]);
    *(uint2*)(p + 8 * g) = make_uint2(h01, h23);
  }
}

// Transposed single-plane combo store: aa*v + bx*Xs + cx*X2s (+ad on diagonal).
__device__ __forceinline__ void store_sc(const f16v v, short* P, int qa, int qb,
                                         int lr, int h, float aa, float bx,
                                         float cx, float ad, const float Xs[16],
                                         const f16v X2s, int diagq) {
  const int off = (32 * qb + lr) * RS + 32 * qa + 4 * h;
  short* p = P + off;
#pragma unroll
  for (int g = 0; g < 4; ++g) {
    float x[4];
#pragma unroll
    for (int t = 0; t < 4; ++t) {
      const int idx = 4 * g + t;
      x[t] = aa * v[idx] + bx * Xs[idx] + cx * X2s[idx];
      if (diagq && (t + 8 * g + 4 * h) == lr) x[t] += ad;
    }
    unsigned h01 = cvt_pk_bf16(x[0], x[1]);
    unsigned h23 = cvt_pk_bf16(x[2], x[3]);
    *(uint2*)(p + 8 * g) = make_uint2(h01, h23);
  }
}

// min-waves = 4: the kernel's live state (av[16]+Xs[16]+X2s+X3s+frags) needs
// ~84 VGPR; forcing 6 blocks/CU (<=64 VGPR) spills to scratch (R7: VGPR=40,
// 1.1 GB scratch writes, 2.4x slower). 4 waves/EU is the natural point.
extern "C" __global__ void __launch_bounds__(256, 4)
logeig_kernel(const float* __restrict__ in, float* __restrict__ out) {
  // 3 LDS planes (26.1 KB).
  // Plane lifecycle:  Yh: X-hi -> G2 (S2)   Yl: X-lo -> W=X^3 (S2)
  //                   Zh: X^2  -> P1 (H)
  __shared__ __align__(16) short sm[3 * PLANE];
  __shared__ float red[4];

  const int b = blockIdx.x, tid = threadIdx.x;
  short* Yh = sm;
  short* Yl = sm + PLANE;
  short* Zh = sm + 2 * PLANE;

  // ---- direct global -> register load (no LDS staging round-trip) ----
  // Thread owns row rr, cols cc*16..+15 (64B/lane chunks; wave covers 4KB).
  const int rr = tid >> 2, cc = tid & 3;
  float av[16];
  {
    const float* Ab = in + (size_t)b * 4096 + rr * 64 + cc * 16;
#pragma unroll
    for (int i = 0; i < 4; ++i) {
      float4 v = *(const float4*)(Ab + 4 * i);
      av[4 * i] = v.x; av[4 * i + 1] = v.y;
      av[4 * i + 2] = v.z; av[4 * i + 3] = v.w;
    }
  }

  // ---- c = ||A||_inf ----
  // A = PSD + I => spectrum(A) subset [1, c] EXACTLY (lmin >= 1, c >= lmax).
  {
    float s = 0.f;
#pragma unroll
    for (int i = 0; i < 16; ++i) s += fabsf(av[i]);
    s += __shfl_xor(s, 1);
    s += __shfl_xor(s, 2);
#pragma unroll
    for (int off = 4; off < 64; off <<= 1) s = fmaxf(s, __shfl_xor(s, off));
    if ((tid & 63) == 0) red[tid >> 6] = s;
  }
  __syncthreads();
  const float c = fmaxf(fmaxf(red[0], red[1]), fmaxf(red[2], red[3]));

  // ---- closed-form degree-9 Chebyshev approx of log on [1,c] ----
  // X = (2A-(c+1)I)/(c-1); log(alpha+beta*x) = 2 log((sqrt(c)+1)/2)
  //   + 2 sum (-1)^{k+1} (tau^k/k) T_k(x),  tau = (sqrt(c)-1)/(sqrt(c)+1).
  const float rtc = sqrtf(c);
  const float tau = (rtc - 1.0f) / (rtc + 1.0f);
  float A[10];
  {
    float tp = tau;
#pragma unroll
    for (int k = 1; k < 10; ++k) {
      A[k] = 2.0f * tp / (float)k * ((k & 1) ? 1.0f : -1.0f);
      tp *= tau;
    }
  }
  const float b0 = 2.0f * logf((rtc + 1.0f) * 0.5f) - A[2] + A[4] - A[6] + A[8];
  const float b1 = A[1] - 3.f * A[3] + 5.f * A[5] - 7.f * A[7] + 9.f * A[9];
  const float b2 = 2.f * A[2] - 8.f * A[4] + 18.f * A[6] - 32.f * A[8];
  const float b3 = 4.f * A[3] - 20.f * A[5] + 56.f * A[7] - 120.f * A[9];
  const float b4 = 8.f * A[4] - 48.f * A[6] + 160.f * A[8];
  const float b5 = 16.f * A[5] - 112.f * A[7] + 432.f * A[9];
  const float b6 = 32.f * A[6] - 256.f * A[8];
  const float b7 = 64.f * A[7] - 576.f * A[9];
  const float b8 = 128.f * A[8];
  const float b9 = 256.f * A[9];

  // ---- split X = (2A-(c+1)I)/(c-1) into bf16 hi/lo planes ----
  {
    const float sc2 = 2.0f / (c - 1.0f);
    const float sh = (c + 1.0f) / (c - 1.0f);
    short* ph = Yh + rr * RS + cc * 16;
    short* pl = Yl + rr * RS + cc * 16;
#pragma unroll
    for (int i = 0; i < 16; i += 4) {
      float y0 = av[i] * sc2 - ((16 * cc + i) == rr ? sh : 0.f);
      float y1 = av[i + 1] * sc2 - ((16 * cc + i + 1) == rr ? sh : 0.f);
      float y2 = av[i + 2] * sc2 - ((16 * cc + i + 2) == rr ? sh : 0.f);
      float y3 = av[i + 3] * sc2 - ((16 * cc + i + 3) == rr ? sh : 0.f);
      unsigned h01 = cvt_pk_bf16(y0, y1);
      unsigned h23 = cvt_pk_bf16(y2, y3);
      unsigned l01 = cvt_pk_bf16(y0 - __uint_as_float(h01 << 16),
                                 y1 - __uint_as_float(h01 & 0xffff0000u));
      unsigned l23 = cvt_pk_bf16(y2 - __uint_as_float(h23 << 16),
                                 y3 - __uint_as_float(h23 & 0xffff0000u));
      *(uint2*)(ph + i) = make_uint2(h01, h23);
      *(uint2*)(pl + i) = make_uint2(l01, l23);
    }
  }
  __syncthreads();

  const int lane = tid & 63, w = tid >> 6;
  const int lr = lane & 31, h = lane >> 5;
  const int qi = w >> 1, qj = w & 1;
  const int dq = (qi == qj);

  // ---- Paterson-Stockmeyer, W = X^3:  p = G0 + G1 W + G2 W^2,
  //      G2 = b6 I + b7 X + b8 X^2 + b9 X^3  (elementwise, no matmul)
  //      G1 = b3 I + b4 X + b5 X^2,   G0 = b0 I + b1 X + b2 X^2.
  //      4 matmuls: X^2 (hi/lo x hi/lo), X^3 (single x hi/lo),
  //                 P1 = G2*W + G1 (single x single), p = P1*W + G0 (single).
  s8v Xjh[4], Xjl[4];   // X@qj frags (hi/lo), cached through S2
  float Xs[16];         // store-layout X values (f32)
  f16v X2s, X3s;        // store-layout X^2 / X^3 values (= MFMA accs, f32)

  // S1: X^2 -> Zh (single); harvest Xs. After this phase both X planes are
  // dead (Xj cached in regs, Xi consumed, Xs harvested).
  {
    load_fs(Yh, Yl, qj, lr, h, Xjh, Xjl);
    {  // Xs: X at the transposed-store positions (row 32qj+lr, col 32qi+4h+8g+t)
      const int off = (32 * qj + lr) * RS + 32 * qi + 4 * h;
#pragma unroll
      for (int g = 0; g < 4; ++g) {
        s4v vh = *(const s4v*)(Yh + off + 8 * g);
        s4v vl = *(const s4v*)(Yl + off + 8 * g);
#pragma unroll
        for (int t = 0; t < 4; ++t) Xs[4 * g + t] = fb(vh[t]) + fb(vl[t]);
      }
    }
    if (dq) {
      X2s = mm3p(Xjh, Xjl, Xjh, Xjl);
    } else {
      s8v Xih[4], Xil[4];
      load_fs(Yh, Yl, qi, lr, h, Xih, Xil);
      X2s = mm3p(Xih, Xil, Xjh, Xjl);  // X^2 quadrant (qi,qj)
    }
    store_s(X2s, Zh, qi, qj, lr, h);
    __syncthreads();
  }

  // S2: X^3 = W -> Yl (X-lo dead); G2 -> Yh (X-hi dead). Reads only Zh + regs.
  {
    s8v X2i[4];
    load_fs1(Zh, qi, lr, h, X2i);
    X3s = mm2p(X2i, Xjh, Xjl);  // X^3 quadrant (qi,qj), 8 MFMAs
    store_s(X3s, Yl, qi, qj, lr, h);
    // G2 = b6 I + b7 X + b8 X^2 + b9 X^3
    store_sc(X3s, Yh, qi, qj, lr, h, b9, b7, b8, b6, Xs, X2s, dq);
    __syncthreads();
  }

  // H: P1 = G2*W + G1 -> Zh (X^2 plane dead: combos use X2s regs).
  s8v Wh[4];  // W = X^3@qj frags, cached for F
  {
    load_fs1(Yl, qj, lr, h, Wh);
    s8v G2i[4];
    load_fs1(Yh, qi, lr, h, G2i);
    f16v q = mm1p(G2i, Wh);  // 4 MFMAs
    store_sc(q, Zh, qi, qj, lr, h, 1.f, b4, b5, b3, Xs, X2s, dq);
    __syncthreads();
  }

  // F (final): L = P1*W + G0 ; abs, sqrt2 off-diag, triu gather.
  // The (qi>qj) wave's quadrant is discarded: skip it.
  if (qi <= qj) {
    s8v P1i[4];
    load_fs1(Zh, qi, lr, h, P1i);
    f16v fq = mm1p(P1i, Wh);  // quadrant (qi,qj), 4 MFMAs
    const float SQ2 = 1.41421356237309515f;
    float* ob = out + (size_t)b * 2080;
#pragma unroll
    for (int g = 0; g < 4; ++g) {
#pragma unroll
      for (int t = 0; t < 4; ++t) {
        int rexpr = t + 8 * g + 4 * h;
        int R = 32 * qi + rexpr, C = 32 * qj + lr;
        if (qi < qj || rexpr <= lr) {
          const int idx = 4 * g + t;
          float v = fq[idx] + b1 * Xs[idx] + b2 * X2s[idx]
                    + ((dq && rexpr == lr) ? b0 : 0.f);
          v = fabsf(v) * ((R == C) ? 1.f : SQ2);
          ob[(size_t)(R * 64 - (R * (R - 1)) / 2 - R) + C] = v;
        }
      }
    }
  }
}

extern "C" void kernel_launch(void* const* d_in, const int* in_sizes, int n_in,
                              void* d_out, int out_size, void* d_ws, size_t ws_size,
                              hipStream_t stream) {
  (void)n_in; (void)d_ws; (void)ws_size; (void)out_size;
  const float* in = (const float*)d_in[0];
  float* out = (float*)d_out;
  const int B = in_sizes[0] / 4096;  // 16384
  hipLaunchKernelGGL(logeig_kernel, dim3(B), dim3(256), 0, stream, in, out);
}

// Round 9
// 392.354 us; speedup vs baseline: 1.8589x; 1.0066x over previous
//
#include <hip/hip_runtime.h>
#include <math.h>

#define PLANE 4352   // 64 rows * 68 shorts
#define RS 68        // row stride (elements); 136 B = 34 banks -> 2-way max, free

typedef short s4v __attribute__((ext_vector_type(4)));
typedef short s8v __attribute__((ext_vector_type(8)));
typedef float f16v __attribute__((ext_vector_type(16)));

__device__ __forceinline__ float fb(short s) {
  return __uint_as_float(((unsigned)(unsigned short)s) << 16);
}

// RNE-packed f32x2 -> bf16x2 (low = e0, high = e1). No builtin on gfx950.
__device__ __forceinline__ unsigned cvt_pk_bf16(float e0, float e1) {
  unsigned r;
  asm("v_cvt_pk_bf16_f32 %0, %1, %2" : "=v"(r) : "v"(e0), "v"(e1));
  return r;
}

// Load hi/lo fragment sets of symmetric matrix quadrant q (X planes):
// lane (lr,h) gets rows 32q+lr, cols ks*16+8h..+7  (A-frag == B-frag by symmetry)
__device__ __forceinline__ void load_fs(const short* Ph, const short* Pl, int q,
                                        int lr, int h, s8v fh[4], s8v fl[4]) {
  const int off = (32 * q + lr) * RS + 8 * h;
  const short* ph = Ph + off;
  const short* pl = Pl + off;
#pragma unroll
  for (int ks = 0; ks < 4; ++ks) {
    s4v a = *(const s4v*)(ph + 16 * ks);
    s4v b = *(const s4v*)(ph + 16 * ks + 4);
    fh[ks] = __builtin_shufflevector(a, b, 0, 1, 2, 3, 4, 5, 6, 7);
    s4v c = *(const s4v*)(pl + 16 * ks);
    s4v d = *(const s4v*)(pl + 16 * ks + 4);
    fl[ks] = __builtin_shufflevector(c, d, 0, 1, 2, 3, 4, 5, 6, 7);
  }
}

// Load single-plane fragment set of symmetric matrix quadrant q
__device__ __forceinline__ void load_fs1(const short* P, int q, int lr, int h,
                                         s8v f[4]) {
  const int off = (32 * q + lr) * RS + 8 * h;
  const short* p = P + off;
#pragma unroll
  for (int ks = 0; ks < 4; ++ks) {
    s4v a = *(const s4v*)(p + 16 * ks);
    s4v b = *(const s4v*)(p + 16 * ks + 4);
    f[ks] = __builtin_shufflevector(a, b, 0, 1, 2, 3, 4, 5, 6, 7);
  }
}

// A,B both hi/lo: 12 MFMAs (drop lo*lo ~ 2^-32)
__device__ __forceinline__ f16v mm3p(const s8v Ah[4], const s8v Al[4],
                                     const s8v Bh[4], const s8v Bl[4]) {
  f16v acc = {0.f, 0.f, 0.f, 0.f, 0.f, 0.f, 0.f, 0.f,
              0.f, 0.f, 0.f, 0.f, 0.f, 0.f, 0.f, 0.f};
#pragma unroll
  for (int ks = 0; ks < 4; ++ks) {
    acc = __builtin_amdgcn_mfma_f32_32x32x16_bf16(Ah[ks], Bh[ks], acc, 0, 0, 0);
    acc = __builtin_amdgcn_mfma_f32_32x32x16_bf16(Ah[ks], Bl[ks], acc, 0, 0, 0);
    acc = __builtin_amdgcn_mfma_f32_32x32x16_bf16(Al[ks], Bh[ks], acc, 0, 0, 0);
  }
  return acc;
}

// A single, B hi/lo: 8 MFMAs
__device__ __forceinline__ f16v mm2p(const s8v Ah[4], const s8v Bh[4],
                                     const s8v Bl[4]) {
  f16v acc = {0.f, 0.f, 0.f, 0.f, 0.f, 0.f, 0.f, 0.f,
              0.f, 0.f, 0.f, 0.f, 0.f, 0.f, 0.f, 0.f};
#pragma unroll
  for (int ks = 0; ks < 4; ++ks) {
    acc = __builtin_amdgcn_mfma_f32_32x32x16_bf16(Ah[ks], Bh[ks], acc, 0, 0, 0);
    acc = __builtin_amdgcn_mfma_f32_32x32x16_bf16(Ah[ks], Bl[ks], acc, 0, 0, 0);
  }
  return acc;
}

// A,B both single: 4 MFMAs
__device__ __forceinline__ f16v mm1p(const s8v Ah[4], const s8v Bh[4]) {
  f16v acc = {0.f, 0.f, 0.f, 0.f, 0.f, 0.f, 0.f, 0.f,
              0.f, 0.f, 0.f, 0.f, 0.f, 0.f, 0.f, 0.f};
#pragma unroll
  for (int ks = 0; ks < 4; ++ks)
    acc = __builtin_amdgcn_mfma_f32_32x32x16_bf16(Ah[ks], Bh[ks], acc, 0, 0, 0);
  return acc;
}

// Transposed single-plane store of quadrant result (symmetric matrices):
// LDS[32qb+lr][32qa + (t+8g+4h)] = v[4g+t] (RNE bf16).
__device__ __forceinline__ void store_s(const f16v v, short* P, int qa, int qb,
                                        int lr, int h) {
  const int off = (32 * qb + lr) * RS + 32 * qa + 4 * h;
  short* p = P + off;
#pragma unroll
  for (int g = 0; g < 4; ++g) {
    unsigned h01 = cvt_pk_bf16(v[4 * g], v[4 * g + 1]);
    unsigned h23 = cvt_pk_bf16(v[4 * g + 2], v[4 * g + 3]);
    *(uint2*)(p + 8 * g) = make_uint2(h01, h23);
  }
}

// Transposed single-plane combo store: aa*v + bx*Xs + cx*X2s + ad*Dd (FMA-based
// diagonal add: Dd is the per-lane indicator of the true-diagonal element).
__device__ __forceinline__ void store_sc(const f16v v, short* P, int qa, int qb,
                                         int lr, int h, float aa, float bx,
                                         float cx, float ad, const float Xs[16],
                                         const f16v X2s, const float Dd[16]) {
  const int off = (32 * qb + lr) * RS + 32 * qa + 4 * h;
  short* p = P + off;
#pragma unroll
  for (int g = 0; g < 4; ++g) {
    float x[4];
#pragma unroll
    for (int t = 0; t < 4; ++t) {
      const int idx = 4 * g + t;
      x[t] = aa * v[idx] + bx * Xs[idx] + cx * X2s[idx] + ad * Dd[idx];
    }
    unsigned h01 = cvt_pk_bf16(x[0], x[1]);
    unsigned h23 = cvt_pk_bf16(x[2], x[3]);
    *(uint2*)(p + 8 * g) = make_uint2(h01, h23);
  }
}

// min-waves = 4: live state needs ~90 VGPR; forcing 6 blocks/CU (<=64 VGPR)
// spills to scratch (R7: VGPR=40, 1.1 GB scratch, 2.4x slower).
extern "C" __global__ void __launch_bounds__(256, 4)
logeig_kernel(const float* __restrict__ in, float* __restrict__ out) {
  // 3 LDS planes (26.1 KB).
  // Plane lifecycle:  Yh: X-hi -> G2 (S2)   Yl: X-lo -> W=X^3 (S2)
  //                   Zh: X^2  -> P1 (H)
  __shared__ __align__(16) short sm[3 * PLANE];
  __shared__ float red[4];
  __shared__ float cb[10];  // block-uniform Chebyshev coefficients b0..b9

  const int b = blockIdx.x, tid = threadIdx.x;
  short* Yh = sm;
  short* Yl = sm + PLANE;
  short* Zh = sm + 2 * PLANE;

  // ---- direct global -> register load (no LDS staging round-trip) ----
  const int rr = tid >> 2, cc = tid & 3;
  float av[16];
  {
    const float* Ab = in + (size_t)b * 4096 + rr * 64 + cc * 16;
#pragma unroll
    for (int i = 0; i < 4; ++i) {
      float4 v = *(const float4*)(Ab + 4 * i);
      av[4 * i] = v.x; av[4 * i + 1] = v.y;
      av[4 * i + 2] = v.z; av[4 * i + 3] = v.w;
    }
  }

  // ---- c = ||A||_inf ----
  // A = PSD + I => spectrum(A) subset [1, c] EXACTLY (lmin >= 1, c >= lmax).
  {
    float s = 0.f;
#pragma unroll
    for (int i = 0; i < 16; ++i) s += fabsf(av[i]);
    s += __shfl_xor(s, 1);
    s += __shfl_xor(s, 2);
#pragma unroll
    for (int off = 4; off < 64; off <<= 1) s = fmaxf(s, __shfl_xor(s, off));
    if ((tid & 63) == 0) red[tid >> 6] = s;
  }
  __syncthreads();
  const float c = fmaxf(fmaxf(red[0], red[1]), fmaxf(red[2], red[3]));

  // ---- degree-9 Chebyshev coefficients: THREAD 0 ONLY (block-uniform) ----
  // X = (2A-(c+1)I)/(c-1); log(alpha+beta*x) = 2 log((sqrt(c)+1)/2)
  //   + 2 sum (-1)^{k+1} (tau^k/k) T_k(x),  tau = (sqrt(c)-1)/(sqrt(c)+1).
  // ~300 serial VALU inst (sqrt/log/divides) -- running it on every thread
  // wastes aggregate VALU issue (we are VALU-bound); broadcast via LDS.
  if (tid == 0) {
    const float rtc = sqrtf(c);
    const float tau = (rtc - 1.0f) / (rtc + 1.0f);
    float A[10];
    float tp = tau;
#pragma unroll
    for (int k = 1; k < 10; ++k) {
      A[k] = 2.0f * tp / (float)k * ((k & 1) ? 1.0f : -1.0f);
      tp *= tau;
    }
    cb[0] = 2.0f * logf((rtc + 1.0f) * 0.5f) - A[2] + A[4] - A[6] + A[8];
    cb[1] = A[1] - 3.f * A[3] + 5.f * A[5] - 7.f * A[7] + 9.f * A[9];
    cb[2] = 2.f * A[2] - 8.f * A[4] + 18.f * A[6] - 32.f * A[8];
    cb[3] = 4.f * A[3] - 20.f * A[5] + 56.f * A[7] - 120.f * A[9];
    cb[4] = 8.f * A[4] - 48.f * A[6] + 160.f * A[8];
    cb[5] = 16.f * A[5] - 112.f * A[7] + 432.f * A[9];
    cb[6] = 32.f * A[6] - 256.f * A[8];
    cb[7] = 64.f * A[7] - 576.f * A[9];
    cb[8] = 128.f * A[8];
    cb[9] = 256.f * A[9];
  }

  // ---- split X = (2A-(c+1)I)/(c-1) into bf16 hi/lo planes ----
  // sh = (c+1)/(c-1) = 1 + 2/(c-1) = 1 + sc2: one divide for all threads.
  {
    const float sc2 = 2.0f / (c - 1.0f);
    const float sh = 1.0f + sc2;
    short* ph = Yh + rr * RS + cc * 16;
    short* pl = Yl + rr * RS + cc * 16;
#pragma unroll
    for (int i = 0; i < 16; i += 4) {
      float y0 = av[i] * sc2 - ((16 * cc + i) == rr ? sh : 0.f);
      float y1 = av[i + 1] * sc2 - ((16 * cc + i + 1) == rr ? sh : 0.f);
      float y2 = av[i + 2] * sc2 - ((16 * cc + i + 2) == rr ? sh : 0.f);
      float y3 = av[i + 3] * sc2 - ((16 * cc + i + 3) == rr ? sh : 0.f);
      unsigned h01 = cvt_pk_bf16(y0, y1);
      unsigned h23 = cvt_pk_bf16(y2, y3);
      unsigned l01 = cvt_pk_bf16(y0 - __uint_as_float(h01 << 16),
                                 y1 - __uint_as_float(h01 & 0xffff0000u));
      unsigned l23 = cvt_pk_bf16(y2 - __uint_as_float(h23 << 16),
                                 y3 - __uint_as_float(h23 & 0xffff0000u));
      *(uint2*)(ph + i) = make_uint2(h01, h23);
      *(uint2*)(pl + i) = make_uint2(l01, l23);
    }
  }
  __syncthreads();

  const int lane = tid & 63, w = tid >> 6;
  const int lr = lane & 31, h = lane >> 5;
  const int qi = w >> 1, qj = w & 1;
  const int dq = (qi == qj);

  // Per-lane diagonal indicator in store layout (computed ONCE; diag adds
  // become FMAs instead of per-store compare+cndmask).
  float Dd[16];
  {
    const int has_d = dq && (((lr >> 2) & 1) == h);
    const int didx = 4 * (lr >> 3) + (lr & 3);
#pragma unroll
    for (int i = 0; i < 16; ++i) Dd[i] = (has_d && i == didx) ? 1.f : 0.f;
  }

  // ---- Paterson-Stockmeyer, W = X^3:  p = G0 + G1 W + G2 W^2,
  //      G2 = b6 I + b7 X + b8 X^2 + b9 X^3  (elementwise, no matmul)
  //      G1 = b3 I + b4 X + b5 X^2,   G0 = b0 I + b1 X + b2 X^2.
  //      4 matmuls: X^2 (hi/lo x hi/lo), X^3 (single x hi/lo),
  //                 P1 = G2*W + G1 (single x single), p = P1*W + G0 (single).
  s8v Xjh[4], Xjl[4];   // X@qj frags (hi/lo), cached through S2
  float Xs[16];         // store-layout X values (f32)
  f16v X2s, X3s;        // store-layout X^2 / X^3 values (= MFMA accs, f32)

  // S1: X^2 -> Zh (single); harvest Xs. After this phase both X planes are
  // dead (Xj cached in regs, Xi consumed, Xs harvested).
  {
    load_fs(Yh, Yl, qj, lr, h, Xjh, Xjl);
    {  // Xs: X at the transposed-store positions (row 32qj+lr, col 32qi+4h+8g+t)
      const int off = (32 * qj + lr) * RS + 32 * qi + 4 * h;
#pragma unroll
      for (int g = 0; g < 4; ++g) {
        s4v vh = *(const s4v*)(Yh + off + 8 * g);
        s4v vl = *(const s4v*)(Yl + off + 8 * g);
#pragma unroll
        for (int t = 0; t < 4; ++t) Xs[4 * g + t] = fb(vh[t]) + fb(vl[t]);
      }
    }
    if (dq) {
      X2s = mm3p(Xjh, Xjl, Xjh, Xjl);
    } else {
      s8v Xih[4], Xil[4];
      load_fs(Yh, Yl, qi, lr, h, Xih, Xil);
      X2s = mm3p(Xih, Xil, Xjh, Xjl);  // X^2 quadrant (qi,qj)
    }
    store_s(X2s, Zh, qi, qj, lr, h);
    __syncthreads();
  }

  // S2: X^3 = W -> Yl (X-lo dead); G2 -> Yh (X-hi dead). Reads only Zh + regs.
  {
    const float b6 = cb[6], b7 = cb[7], b8 = cb[8], b9 = cb[9];
    s8v X2i[4];
    load_fs1(Zh, qi, lr, h, X2i);
    X3s = mm2p(X2i, Xjh, Xjl);  // X^3 quadrant (qi,qj), 8 MFMAs
    store_s(X3s, Yl, qi, qj, lr, h);
    // G2 = b6 I + b7 X + b8 X^2 + b9 X^3
    store_sc(X3s, Yh, qi, qj, lr, h, b9, b7, b8, b6, Xs, X2s, Dd);
    __syncthreads();
  }

  // H: P1 = G2*W + G1 -> Zh (X^2 plane dead: combos use X2s regs).
  s8v Wh[4];  // W = X^3@qj frags, cached for F
  {
    const float b3 = cb[3], b4 = cb[4], b5 = cb[5];
    load_fs1(Yl, qj, lr, h, Wh);
    s8v G2i[4];
    load_fs1(Yh, qi, lr, h, G2i);
    f16v q = mm1p(G2i, Wh);  // 4 MFMAs
    store_sc(q, Zh, qi, qj, lr, h, 1.f, b4, b5, b3, Xs, X2s, Dd);
    __syncthreads();
  }

  // F (final): L = P1*W + G0 ; abs, sqrt2 off-diag, triu gather.
  // The (qi>qj) wave's quadrant is discarded: skip it.
  if (qi <= qj) {
    const float b0 = cb[0], b1 = cb[1], b2 = cb[2];
    s8v P1i[4];
    load_fs1(Zh, qi, lr, h, P1i);
    f16v fq = mm1p(P1i, Wh);  // quadrant (qi,qj), 4 MFMAs
    const float SQ2 = 1.41421356237309515f;
    float* ob = out + (size_t)b * 2080;
#pragma unroll
    for (int g = 0; g < 4; ++g) {
#pragma unroll
      for (int t = 0; t < 4; ++t) {
        int rexpr = t + 8 * g + 4 * h;
        int R = 32 * qi + rexpr, C = 32 * qj + lr;
        if (qi < qj || rexpr <= lr) {
          const int idx = 4 * g + t;
          float v = fq[idx] + b1 * Xs[idx] + b2 * X2s[idx] + b0 * Dd[idx];
          v = fabsf(v) * ((R == C) ? 1.f : SQ2);
          ob[(size_t)(R * 64 - (R * (R - 1)) / 2 - R) + C] = v;
        }
      }
    }
  }
}

extern "C" void kernel_launch(void* const* d_in, const int* in_sizes, int n_in,
                              void* d_out, int out_size, void* d_ws, size_t ws_size,
                              hipStream_t stream) {
  (void)n_in; (void)d_ws; (void)ws_size; (void)out_size;
  const float* in = (const float*)d_in[0];
  float* out = (float*)d_out;
  const int B = in_sizes[0] / 4096;  // 16384
  hipLaunchKernelGGL(logeig_kernel, dim3(B), dim3(256), 0, stream, in, out);
}